// Round 11
// baseline (164.755 us; speedup 1.0000x reference)
//
#include <hip/hip_runtime.h>
#include <hip/hip_fp16.h>
#include <math.h>

#define HIDDEN 128
#define NSTEP  64
#define BATCH2 4096
#define OUTD   100

typedef __attribute__((ext_vector_type(8))) _Float16 f16x8;
typedef __attribute__((ext_vector_type(4))) float    f32x4;

static __device__ __forceinline__ f32x4 mfma32(f16x8 a, f16x8 b, f32x4 c) {
    return __builtin_amdgcn_mfma_f32_16x16x32_f16(a, b, c, 0, 0, 0);
}
static __device__ __forceinline__ unsigned h2u(__half2 h) {
    return __builtin_bit_cast(unsigned, h);
}
static __device__ __forceinline__ __half2 u2h(unsigned u) {
    return __builtin_bit_cast(__half2, u);
}
static __device__ __forceinline__ f16x8 frag8(__half2 a, __half2 b, __half2 c, __half2 d) {
    uint4 p = { h2u(a), h2u(b), h2u(c), h2u(d) };
    return __builtin_bit_cast(f16x8, p);
}
static __device__ __forceinline__ f16x8 catu2(uint2 lo, uint2 hi) {
    uint4 p = { lo.x, lo.y, hi.x, hi.y };
    return __builtin_bit_cast(f16x8, p);
}

// direct global->LDS DMA: lane i's 16B lands at ldsbase + 16*i
static __device__ __forceinline__ void load_lds16(const void* g, void* l) {
    __builtin_amdgcn_global_load_lds(
        (const __attribute__((address_space(1))) void*)g,
        (__attribute__((address_space(3))) void*)l, 16, 0, 0);
}

// packed-f16 tanh value+1st+2nd tangent chain (2 units per call)
// w = 2/(1+e^{2z}); a = 1-w; g = w(2-w); ad = g zd; add = g zdd - 2 a zd ad
static __device__ __forceinline__ void tanh_chain_h2(
    __half2 z, __half2 zd, __half2 zdd,
    __half2& a, __half2& ad, __half2& add)
{
    const __half2 one = __float2half2_rn(1.0f);
    const __half2 two = __float2half2_rn(2.0f);
    __half2 e = h2exp(__hadd2(z, z));
    __half2 w = __hmul2(two, h2rcp(__hadd2(e, one)));
    a  = __hsub2(one, w);
    __half2 g = __hmul2(w, __hsub2(two, w));
    ad = __hmul2(g, zd);
    __half2 p = __hmul2(a, zd);
    __half2 u = __hadd2(p, p);
    add = __hsub2(__hmul2(g, zdd), __hmul2(u, ad));
}

// d_ws layout (halfs):
//  [0..16383]     W2 image, K32 A-layout: chunk(mt,c)=mt*4+c, lane L, elem i:
//                 A[m=16mt+(L&15)][k=32c+8(L>>4)+i] = W2[k][m]
//  [16384..32767] W3 image, same physical layout but k-cols permuted by sigma:
//                 kappa=32c+8q+i holds logical lg=32c+16(i>>2)+4q+(i&3)
//                 (so the K32 B-frag == concat of two K16-style C-frag uint2s)
//  [32768..45567] W4T[100][128]
__global__ __launch_bounds__(256) void setup_kernel(
    const float* __restrict__ W2, const float* __restrict__ W3,
    const float* __restrict__ W4,
    const float* __restrict__ samples_s,
    __half* __restrict__ wbf, float* __restrict__ out)
{
    int t = blockIdx.x * blockDim.x + threadIdx.x;   // 0..32767
    int l   = t >> 14;
    int pos = t & 16383;
    int c    = (pos >> 9) & 3;          // k-chunk
    int lane = (pos >> 3) & 63;
    int i    = pos & 7;
    int m    = ((pos >> 11) << 4) + (lane & 15);     // 16*mt + (lane&15)
    int q    = lane >> 4;
    float v;
    if (l == 0) {
        int k = 32 * c + 8 * q + i;
        v = W2[k * HIDDEN + m];
    } else {
        int lg = 32 * c + 16 * (i >> 2) + 4 * q + (i & 3);
        v = W3[lg * HIDDEN + m];
    }
    wbf[t] = __float2half(v);
    if (t < OUTD * HIDDEN) {                         // W4T[n][h] = W4[h][n]
        int nn = t >> 7, h = t & 127;
        wbf[32768 + t] = __float2half(W4[h * OUTD + nn]);
    }
    if (t < BATCH2) {
        out[t] = 0.0f;
        float s0 = samples_s[t * (NSTEP + 1)];
        out[BATCH2 + t] = 3.9894228040143267f * expf(-500000.0f * s0 * s0);
    }
}

// One block = one sample = 64 evals. Wave w owns evals j = 16w + (lane&15);
// quad q holds K32 k-slice {32c + 8q + i}. Activations stay in registers as
// packed f16; layer-N C-frag pairs concatenate directly into layer-N+1 K32
// B-frags (hidden-space relabeling baked into the W3 image). Biases are MFMA
// accumulator init. LDS = exactly 32 KB -> 5 blocks/CU.
__global__ __launch_bounds__(256, 5) void eval_kernel(
    const float* __restrict__ W1, const float* __restrict__ b1,
    const float* __restrict__ b2, const float* __restrict__ b3,
    const float* __restrict__ b4,
    const __half* __restrict__ wbf,
    const int*   __restrict__ samples_n,
    const float* __restrict__ samples_s,
    const float* __restrict__ samples_dB,
    const float* __restrict__ tptr,
    float* __restrict__ out)
{
    __shared__ __align__(16) short ldsW[HIDDEN * HIDDEN];  // 32 KB, one layer image

    const int tid  = threadIdx.x;
    const int w    = tid >> 6;
    const int lane = tid & 63;
    const int m16  = lane & 15;
    const int q    = lane >> 4;
    const int b    = blockIdx.x;

    // ---- stage layer-2 image (wave w: 1-KB chunks 8w..8w+7) ----
    {
        const short* g2 = (const short*)wbf;
        #pragma unroll
        for (int it = 0; it < 8; ++it) {
            int idx = w * 8 + it;
            load_lds16(g2 + idx * 512 + lane * 8, ldsW + idx * 512);
        }
    }

    // per-eval scalars
    const float t  = tptr[0];
    const float dt = t / (float)NSTEP;
    const int   j  = 16 * w + m16;
    const int   c  = NSTEP - j;
    const float s  = samples_s[b * (NSTEP + 1) + c];
    const int   n  = samples_n[b * (NSTEP + 1) + c];
    const float dB = samples_dB[b * NSTEP + (NSTEP - 1 - j)];
    const float tk = (j == 0) ? t : t - dt * (float)(j - 1);

    // ---- layer 1: K32 B-fragments directly (h = 32c + 8q + i, i=0..7) ----
    f16x8 B1v[4], B1d[4], B1dd[4];
    const __half2 zero2 = __float2half2_rn(0.0f);
    #pragma unroll
    for (int ck = 0; ck < 4; ++ck) {
        const int h0 = 32 * ck + 8 * q;
        float4 wa0 = *(const float4*)(W1 + h0);
        float4 wa1 = *(const float4*)(W1 + h0 + 4);
        float4 wb0 = *(const float4*)(W1 + HIDDEN + h0);
        float4 wb1 = *(const float4*)(W1 + HIDDEN + h0 + 4);
        float4 bb0 = *(const float4*)(b1 + h0);
        float4 bb1 = *(const float4*)(b1 + h0 + 4);
        __half2 a[4], ad[4], add[4];
        {
            __half2 z  = __floats2half2_rn(fmaf(wa0.x, s, fmaf(wb0.x, tk, bb0.x)),
                                           fmaf(wa0.y, s, fmaf(wb0.y, tk, bb0.y)));
            tanh_chain_h2(z, __floats2half2_rn(wa0.x, wa0.y), zero2, a[0], ad[0], add[0]);
            z  = __floats2half2_rn(fmaf(wa0.z, s, fmaf(wb0.z, tk, bb0.z)),
                                   fmaf(wa0.w, s, fmaf(wb0.w, tk, bb0.w)));
            tanh_chain_h2(z, __floats2half2_rn(wa0.z, wa0.w), zero2, a[1], ad[1], add[1]);
            z  = __floats2half2_rn(fmaf(wa1.x, s, fmaf(wb1.x, tk, bb1.x)),
                                   fmaf(wa1.y, s, fmaf(wb1.y, tk, bb1.y)));
            tanh_chain_h2(z, __floats2half2_rn(wa1.x, wa1.y), zero2, a[2], ad[2], add[2]);
            z  = __floats2half2_rn(fmaf(wa1.z, s, fmaf(wb1.z, tk, bb1.z)),
                                   fmaf(wa1.w, s, fmaf(wb1.w, tk, bb1.w)));
            tanh_chain_h2(z, __floats2half2_rn(wa1.z, wa1.w), zero2, a[3], ad[3], add[3]);
        }
        B1v[ck]  = frag8(a[0],  a[1],  a[2],  a[3]);
        B1d[ck]  = frag8(ad[0], ad[1], ad[2], ad[3]);
        B1dd[ck] = frag8(add[0], add[1], add[2], add[3]);
    }

    __syncthreads();   // layer-2 image visible (drains vmcnt)

    // ---- layer 2: K32 MFMA (bias as acc-init) + epilogue -> uint2 slots ----
    uint2 Nv[8], Nd[8], Ndd[8];
    #pragma unroll
    for (int mt = 0; mt < 8; ++mt) {
        const int h0 = 16 * mt + 4 * q;
        float4 bias = *(const float4*)(b2 + h0);
        f32x4 aV = {bias.x, bias.y, bias.z, bias.w};
        f32x4 aD = {0.f,0.f,0.f,0.f}, aDD = {0.f,0.f,0.f,0.f};
        #pragma unroll
        for (int ck = 0; ck < 4; ++ck) {
            f16x8 aw = *(const f16x8*)(ldsW + ((mt * 4 + ck) << 9) + (lane << 3));
            aV  = mfma32(aw, B1v[ck],  aV );
            aD  = mfma32(aw, B1d[ck],  aD );
            aDD = mfma32(aw, B1dd[ck], aDD);
        }
        __half2 a0, ad0, add0, a1, ad1, add1;
        tanh_chain_h2(__floats2half2_rn(aV[0], aV[1]),
                      __floats2half2_rn(aD[0], aD[1]),
                      __floats2half2_rn(aDD[0], aDD[1]), a0, ad0, add0);
        tanh_chain_h2(__floats2half2_rn(aV[2], aV[3]),
                      __floats2half2_rn(aD[2], aD[3]),
                      __floats2half2_rn(aDD[2], aDD[3]), a1, ad1, add1);
        Nv[mt]  = (uint2){ h2u(a0),  h2u(a1)  };
        Nd[mt]  = (uint2){ h2u(ad0), h2u(ad1) };
        Ndd[mt] = (uint2){ h2u(add0), h2u(add1) };
    }

    __syncthreads();   // layer-2 weight reads done

    // ---- stage layer-3 image ----
    {
        const short* g3 = (const short*)(wbf + HIDDEN * HIDDEN);
        #pragma unroll
        for (int it = 0; it < 8; ++it) {
            int idx = w * 8 + it;
            load_lds16(g3 + idx * 512 + lane * 8, ldsW + idx * 512);
        }
    }

    // build layer-3 K32 B-frags: pure register concatenation (sigma-permuted image)
    f16x8 B2v[4], B2d[4], B2dd[4];
    #pragma unroll
    for (int ck = 0; ck < 4; ++ck) {
        B2v[ck]  = catu2(Nv[2*ck],  Nv[2*ck+1]);
        B2d[ck]  = catu2(Nd[2*ck],  Nd[2*ck+1]);
        B2dd[ck] = catu2(Ndd[2*ck], Ndd[2*ck+1]);
    }
    __syncthreads();   // layer-3 image visible

    // ---- layer 3 + fused layer 4 (packed-f16 dot) ----
    const __half* __restrict__ w4t = wbf + 2 * HIDDEN * HIDDEN;
    __half2 accV = zero2, accD = zero2, accDD = zero2;
    #pragma unroll
    for (int mt = 0; mt < 8; ++mt) {
        const int h0 = 16 * mt + 4 * q;
        float4 bias = *(const float4*)(b3 + h0);
        f32x4 aV = {bias.x, bias.y, bias.z, bias.w};
        f32x4 aD = {0.f,0.f,0.f,0.f}, aDD = {0.f,0.f,0.f,0.f};
        #pragma unroll
        for (int ck = 0; ck < 4; ++ck) {
            f16x8 aw = *(const f16x8*)(ldsW + ((mt * 4 + ck) << 9) + (lane << 3));
            aV  = mfma32(aw, B2v[ck],  aV );
            aD  = mfma32(aw, B2d[ck],  aD );
            aDD = mfma32(aw, B2dd[ck], aDD);
        }
        uint2 w4u = *(const uint2*)(w4t + n * HIDDEN + h0);   // f16 W4T[n][h0..h0+3]
        __half2 w4lo = u2h(w4u.x), w4hi = u2h(w4u.y);
        __half2 a0, ad0, add0, a1, ad1, add1;
        tanh_chain_h2(__floats2half2_rn(aV[0], aV[1]),
                      __floats2half2_rn(aD[0], aD[1]),
                      __floats2half2_rn(aDD[0], aDD[1]), a0, ad0, add0);
        tanh_chain_h2(__floats2half2_rn(aV[2], aV[3]),
                      __floats2half2_rn(aD[2], aD[3]),
                      __floats2half2_rn(aDD[2], aDD[3]), a1, ad1, add1);
        accV  = __hfma2(a0,  w4lo, accV );  accV  = __hfma2(a1,  w4hi, accV );
        accD  = __hfma2(ad0, w4lo, accD );  accD  = __hfma2(ad1, w4hi, accD );
        accDD = __hfma2(add0, w4lo, accDD); accDD = __hfma2(add1, w4hi, accDD);
    }
    float sv  = __low2float(accV)  + __high2float(accV);
    float sd  = __low2float(accD)  + __high2float(accD);
    float sdd = __low2float(accDD) + __high2float(accDD);

    // ---- reduce across the 4 quads of each eval ----
    sd  += __shfl_xor(sd,  16, 64);  sd  += __shfl_xor(sd,  32, 64);
    sdd += __shfl_xor(sdd, 16, 64);  sdd += __shfl_xor(sdd, 32, 64);
    sv  += __shfl_xor(sv,  16, 64);  sv  += __shfl_xor(sv,  32, 64);

    float contrib = -(sd * dB + sdd * dt * 0.5f);
    if (j == 0) contrib += sv + b4[n];

    // sum the wave's 16 evals (each 16-lane group holds a duplicate set)
    contrib += __shfl_xor(contrib, 1, 64);
    contrib += __shfl_xor(contrib, 2, 64);
    contrib += __shfl_xor(contrib, 4, 64);
    contrib += __shfl_xor(contrib, 8, 64);
    if (lane == 0) atomicAdd(&out[b], contrib);
}

extern "C" void kernel_launch(void* const* d_in, const int* in_sizes, int n_in,
                              void* d_out, int out_size, void* d_ws, size_t ws_size,
                              hipStream_t stream) {
    const float* W1 = (const float*)d_in[0];
    const float* b1 = (const float*)d_in[1];
    const float* W2 = (const float*)d_in[2];
    const float* b2 = (const float*)d_in[3];
    const float* W3 = (const float*)d_in[4];
    const float* b3 = (const float*)d_in[5];
    const float* W4 = (const float*)d_in[6];
    const float* b4 = (const float*)d_in[7];
    const int*   sn  = (const int*)d_in[8];
    const float* ss  = (const float*)d_in[9];
    const float* sdB = (const float*)d_in[10];
    const float* t   = (const float*)d_in[11];
    float* out = (float*)d_out;
    __half* wbf = (__half*)d_ws;   // 90 KB: W2/W3 K32 MFMA images + W4^T (f16)

    setup_kernel<<<(2 * HIDDEN * HIDDEN) / 256, 256, 0, stream>>>(W2, W3, W4, ss, wbf, out);
    eval_kernel<<<BATCH2, 256, 0, stream>>>(
        W1, b1, b2, b3, b4, wbf, sn, ss, sdB, t, out);
}

// Round 12
// 147.613 us; speedup vs baseline: 1.1161x; 1.1161x over previous
//
#include <hip/hip_runtime.h>
#include <hip/hip_fp16.h>
#include <math.h>

#define HIDDEN 128
#define NSTEP  64
#define BATCH2 4096
#define OUTD   100

typedef __attribute__((ext_vector_type(8))) _Float16 f16x8;
typedef __attribute__((ext_vector_type(4))) float    f32x4;

static __device__ __forceinline__ f32x4 mfma32(f16x8 a, f16x8 b, f32x4 c) {
    return __builtin_amdgcn_mfma_f32_16x16x32_f16(a, b, c, 0, 0, 0);
}
static __device__ __forceinline__ unsigned h2u(__half2 h) {
    return __builtin_bit_cast(unsigned, h);
}
static __device__ __forceinline__ __half2 u2h(unsigned u) {
    return __builtin_bit_cast(__half2, u);
}
static __device__ __forceinline__ f16x8 frag8(__half2 a, __half2 b, __half2 c, __half2 d) {
    uint4 p = { h2u(a), h2u(b), h2u(c), h2u(d) };
    return __builtin_bit_cast(f16x8, p);
}
static __device__ __forceinline__ f16x8 catu2(uint2 lo, uint2 hi) {
    uint4 p = { lo.x, lo.y, hi.x, hi.y };
    return __builtin_bit_cast(f16x8, p);
}

// direct global->LDS DMA: lane i's 16B lands at ldsbase + 16*i
static __device__ __forceinline__ void load_lds16(const void* g, void* l) {
    __builtin_amdgcn_global_load_lds(
        (const __attribute__((address_space(1))) void*)g,
        (__attribute__((address_space(3))) void*)l, 16, 0, 0);
}

// packed-f16 tanh value+1st+2nd tangent chain (2 units per call)
// w = 2/(1+e^{2z}); a = 1-w; g = w(2-w); ad = g zd; add = g zdd - 2 a zd ad
static __device__ __forceinline__ void tanh_chain_h2(
    __half2 z, __half2 zd, __half2 zdd,
    __half2& a, __half2& ad, __half2& add)
{
    const __half2 one = __float2half2_rn(1.0f);
    const __half2 two = __float2half2_rn(2.0f);
    __half2 e = h2exp(__hadd2(z, z));
    __half2 w = __hmul2(two, h2rcp(__hadd2(e, one)));
    a  = __hsub2(one, w);
    __half2 g = __hmul2(w, __hsub2(two, w));
    ad = __hmul2(g, zd);
    __half2 p = __hmul2(a, zd);
    __half2 u = __hadd2(p, p);
    add = __hsub2(__hmul2(g, zdd), __hmul2(u, ad));
}

// d_ws layout (halfs):
//  [0..16383]     W2 image, K32 A-layout: chunk(mt,c)=mt*4+c, lane L, elem i:
//                 A[m=16mt+(L&15)][k=32c+8(L>>4)+i] = W2[k][m]
//  [16384..32767] W3 image, same physical layout but k-cols permuted by sigma:
//                 kappa=32c+8q+i holds logical lg=32c+16(i>>2)+4q+(i&3)
//                 (so the K32 B-frag == concat of two K16-style C-frag uint2s)
//  [32768..45567] W4T[100][128]
__global__ __launch_bounds__(256) void setup_kernel(
    const float* __restrict__ W2, const float* __restrict__ W3,
    const float* __restrict__ W4,
    const float* __restrict__ samples_s,
    __half* __restrict__ wbf, float* __restrict__ out)
{
    int t = blockIdx.x * blockDim.x + threadIdx.x;   // 0..32767
    int l   = t >> 14;
    int pos = t & 16383;
    int c    = (pos >> 9) & 3;          // k-chunk
    int lane = (pos >> 3) & 63;
    int i    = pos & 7;
    int m    = ((pos >> 11) << 4) + (lane & 15);     // 16*mt + (lane&15)
    int q    = lane >> 4;
    float v;
    if (l == 0) {
        int k = 32 * c + 8 * q + i;
        v = W2[k * HIDDEN + m];
    } else {
        int lg = 32 * c + 16 * (i >> 2) + 4 * q + (i & 3);
        v = W3[lg * HIDDEN + m];
    }
    wbf[t] = __float2half(v);
    if (t < OUTD * HIDDEN) {                         // W4T[n][h] = W4[h][n]
        int nn = t >> 7, h = t & 127;
        wbf[32768 + t] = __float2half(W4[h * OUTD + nn]);
    }
    if (t < BATCH2) {
        out[t] = 0.0f;
        float s0 = samples_s[t * (NSTEP + 1)];
        out[BATCH2 + t] = 3.9894228040143267f * expf(-500000.0f * s0 * s0);
    }
}

// One block = one sample = 64 evals. Wave w owns evals j = 16w + (lane&15);
// quad q holds K32 k-slice {32c + 8q + i}. Activations stay in registers as
// packed f16; layer-N C-frag pairs concatenate directly into layer-N+1 K32
// B-frags (hidden-space relabeling baked into the W3 image). Biases are MFMA
// accumulator init. __launch_bounds__(256,4): 128-VGPR budget fits the ~115
// live set ((256,5) forced a 48-VGPR cap -> 123 MB of scratch spill in R11).
__global__ __launch_bounds__(256, 4) void eval_kernel(
    const float* __restrict__ W1, const float* __restrict__ b1,
    const float* __restrict__ b2, const float* __restrict__ b3,
    const float* __restrict__ b4,
    const __half* __restrict__ wbf,
    const int*   __restrict__ samples_n,
    const float* __restrict__ samples_s,
    const float* __restrict__ samples_dB,
    const float* __restrict__ tptr,
    float* __restrict__ out)
{
    __shared__ __align__(16) short ldsW[HIDDEN * HIDDEN];  // 32 KB, one layer image

    const int tid  = threadIdx.x;
    const int w    = tid >> 6;
    const int lane = tid & 63;
    const int m16  = lane & 15;
    const int q    = lane >> 4;
    const int b    = blockIdx.x;

    // ---- stage layer-2 image (wave w: 1-KB chunks 8w..8w+7) ----
    {
        const short* g2 = (const short*)wbf;
        #pragma unroll
        for (int it = 0; it < 8; ++it) {
            int idx = w * 8 + it;
            load_lds16(g2 + idx * 512 + lane * 8, ldsW + idx * 512);
        }
    }

    // per-eval scalars
    const float t  = tptr[0];
    const float dt = t / (float)NSTEP;
    const int   j  = 16 * w + m16;
    const int   c  = NSTEP - j;
    const float s  = samples_s[b * (NSTEP + 1) + c];
    const int   n  = samples_n[b * (NSTEP + 1) + c];
    const float dB = samples_dB[b * NSTEP + (NSTEP - 1 - j)];
    const float tk = (j == 0) ? t : t - dt * (float)(j - 1);

    // ---- layer 1: K32 B-fragments directly (h = 32c + 8q + i, i=0..7) ----
    f16x8 B1v[4], B1d[4], B1dd[4];
    const __half2 zero2 = __float2half2_rn(0.0f);
    #pragma unroll
    for (int ck = 0; ck < 4; ++ck) {
        const int h0 = 32 * ck + 8 * q;
        float4 wa0 = *(const float4*)(W1 + h0);
        float4 wa1 = *(const float4*)(W1 + h0 + 4);
        float4 wb0 = *(const float4*)(W1 + HIDDEN + h0);
        float4 wb1 = *(const float4*)(W1 + HIDDEN + h0 + 4);
        float4 bb0 = *(const float4*)(b1 + h0);
        float4 bb1 = *(const float4*)(b1 + h0 + 4);
        __half2 a[4], ad[4], add[4];
        {
            __half2 z  = __floats2half2_rn(fmaf(wa0.x, s, fmaf(wb0.x, tk, bb0.x)),
                                           fmaf(wa0.y, s, fmaf(wb0.y, tk, bb0.y)));
            tanh_chain_h2(z, __floats2half2_rn(wa0.x, wa0.y), zero2, a[0], ad[0], add[0]);
            z  = __floats2half2_rn(fmaf(wa0.z, s, fmaf(wb0.z, tk, bb0.z)),
                                   fmaf(wa0.w, s, fmaf(wb0.w, tk, bb0.w)));
            tanh_chain_h2(z, __floats2half2_rn(wa0.z, wa0.w), zero2, a[1], ad[1], add[1]);
            z  = __floats2half2_rn(fmaf(wa1.x, s, fmaf(wb1.x, tk, bb1.x)),
                                   fmaf(wa1.y, s, fmaf(wb1.y, tk, bb1.y)));
            tanh_chain_h2(z, __floats2half2_rn(wa1.x, wa1.y), zero2, a[2], ad[2], add[2]);
            z  = __floats2half2_rn(fmaf(wa1.z, s, fmaf(wb1.z, tk, bb1.z)),
                                   fmaf(wa1.w, s, fmaf(wb1.w, tk, bb1.w)));
            tanh_chain_h2(z, __floats2half2_rn(wa1.z, wa1.w), zero2, a[3], ad[3], add[3]);
        }
        B1v[ck]  = frag8(a[0],  a[1],  a[2],  a[3]);
        B1d[ck]  = frag8(ad[0], ad[1], ad[2], ad[3]);
        B1dd[ck] = frag8(add[0], add[1], add[2], add[3]);
    }

    __syncthreads();   // layer-2 image visible (drains vmcnt)

    // ---- layer 2: K32 MFMA (bias as acc-init) + epilogue -> uint2 slots ----
    uint2 Nv[8], Nd[8], Ndd[8];
    #pragma unroll
    for (int mt = 0; mt < 8; ++mt) {
        const int h0 = 16 * mt + 4 * q;
        float4 bias = *(const float4*)(b2 + h0);
        f32x4 aV = {bias.x, bias.y, bias.z, bias.w};
        f32x4 aD = {0.f,0.f,0.f,0.f}, aDD = {0.f,0.f,0.f,0.f};
        #pragma unroll
        for (int ck = 0; ck < 4; ++ck) {
            f16x8 aw = *(const f16x8*)(ldsW + ((mt * 4 + ck) << 9) + (lane << 3));
            aV  = mfma32(aw, B1v[ck],  aV );
            aD  = mfma32(aw, B1d[ck],  aD );
            aDD = mfma32(aw, B1dd[ck], aDD);
        }
        __half2 a0, ad0, add0, a1, ad1, add1;
        tanh_chain_h2(__floats2half2_rn(aV[0], aV[1]),
                      __floats2half2_rn(aD[0], aD[1]),
                      __floats2half2_rn(aDD[0], aDD[1]), a0, ad0, add0);
        tanh_chain_h2(__floats2half2_rn(aV[2], aV[3]),
                      __floats2half2_rn(aD[2], aD[3]),
                      __floats2half2_rn(aDD[2], aDD[3]), a1, ad1, add1);
        Nv[mt]  = (uint2){ h2u(a0),  h2u(a1)  };
        Nd[mt]  = (uint2){ h2u(ad0), h2u(ad1) };
        Ndd[mt] = (uint2){ h2u(add0), h2u(add1) };
    }

    __syncthreads();   // layer-2 weight reads done

    // ---- stage layer-3 image ----
    {
        const short* g3 = (const short*)(wbf + HIDDEN * HIDDEN);
        #pragma unroll
        for (int it = 0; it < 8; ++it) {
            int idx = w * 8 + it;
            load_lds16(g3 + idx * 512 + lane * 8, ldsW + idx * 512);
        }
    }

    // build layer-3 K32 B-frags: pure register concatenation (sigma-permuted image)
    f16x8 B2v[4], B2d[4], B2dd[4];
    #pragma unroll
    for (int ck = 0; ck < 4; ++ck) {
        B2v[ck]  = catu2(Nv[2*ck],  Nv[2*ck+1]);
        B2d[ck]  = catu2(Nd[2*ck],  Nd[2*ck+1]);
        B2dd[ck] = catu2(Ndd[2*ck], Ndd[2*ck+1]);
    }
    __syncthreads();   // layer-3 image visible

    // ---- layer 3 + fused layer 4 (packed-f16 dot) ----
    const __half* __restrict__ w4t = wbf + 2 * HIDDEN * HIDDEN;
    __half2 accV = zero2, accD = zero2, accDD = zero2;
    #pragma unroll
    for (int mt = 0; mt < 8; ++mt) {
        const int h0 = 16 * mt + 4 * q;
        float4 bias = *(const float4*)(b3 + h0);
        f32x4 aV = {bias.x, bias.y, bias.z, bias.w};
        f32x4 aD = {0.f,0.f,0.f,0.f}, aDD = {0.f,0.f,0.f,0.f};
        #pragma unroll
        for (int ck = 0; ck < 4; ++ck) {
            f16x8 aw = *(const f16x8*)(ldsW + ((mt * 4 + ck) << 9) + (lane << 3));
            aV  = mfma32(aw, B2v[ck],  aV );
            aD  = mfma32(aw, B2d[ck],  aD );
            aDD = mfma32(aw, B2dd[ck], aDD);
        }
        uint2 w4u = *(const uint2*)(w4t + n * HIDDEN + h0);   // f16 W4T[n][h0..h0+3]
        __half2 w4lo = u2h(w4u.x), w4hi = u2h(w4u.y);
        __half2 a0, ad0, add0, a1, ad1, add1;
        tanh_chain_h2(__floats2half2_rn(aV[0], aV[1]),
                      __floats2half2_rn(aD[0], aD[1]),
                      __floats2half2_rn(aDD[0], aDD[1]), a0, ad0, add0);
        tanh_chain_h2(__floats2half2_rn(aV[2], aV[3]),
                      __floats2half2_rn(aD[2], aD[3]),
                      __floats2half2_rn(aDD[2], aDD[3]), a1, ad1, add1);
        accV  = __hfma2(a0,  w4lo, accV );  accV  = __hfma2(a1,  w4hi, accV );
        accD  = __hfma2(ad0, w4lo, accD );  accD  = __hfma2(ad1, w4hi, accD );
        accDD = __hfma2(add0, w4lo, accDD); accDD = __hfma2(add1, w4hi, accDD);
    }
    float sv  = __low2float(accV)  + __high2float(accV);
    float sd  = __low2float(accD)  + __high2float(accD);
    float sdd = __low2float(accDD) + __high2float(accDD);

    // ---- reduce across the 4 quads of each eval ----
    sd  += __shfl_xor(sd,  16, 64);  sd  += __shfl_xor(sd,  32, 64);
    sdd += __shfl_xor(sdd, 16, 64);  sdd += __shfl_xor(sdd, 32, 64);
    sv  += __shfl_xor(sv,  16, 64);  sv  += __shfl_xor(sv,  32, 64);

    float contrib = -(sd * dB + sdd * dt * 0.5f);
    if (j == 0) contrib += sv + b4[n];

    // sum the wave's 16 evals (each 16-lane group holds a duplicate set)
    contrib += __shfl_xor(contrib, 1, 64);
    contrib += __shfl_xor(contrib, 2, 64);
    contrib += __shfl_xor(contrib, 4, 64);
    contrib += __shfl_xor(contrib, 8, 64);
    if (lane == 0) atomicAdd(&out[b], contrib);
}

extern "C" void kernel_launch(void* const* d_in, const int* in_sizes, int n_in,
                              void* d_out, int out_size, void* d_ws, size_t ws_size,
                              hipStream_t stream) {
    const float* W1 = (const float*)d_in[0];
    const float* b1 = (const float*)d_in[1];
    const float* W2 = (const float*)d_in[2];
    const float* b2 = (const float*)d_in[3];
    const float* W3 = (const float*)d_in[4];
    const float* b3 = (const float*)d_in[5];
    const float* W4 = (const float*)d_in[6];
    const float* b4 = (const float*)d_in[7];
    const int*   sn  = (const int*)d_in[8];
    const float* ss  = (const float*)d_in[9];
    const float* sdB = (const float*)d_in[10];
    const float* t   = (const float*)d_in[11];
    float* out = (float*)d_out;
    __half* wbf = (__half*)d_ws;   // 90 KB: W2/W3 K32 MFMA images + W4^T (f16)

    setup_kernel<<<(2 * HIDDEN * HIDDEN) / 256, 256, 0, stream>>>(W2, W3, W4, ss, wbf, out);
    eval_kernel<<<BATCH2, 256, 0, stream>>>(
        W1, b1, b2, b3, b4, wbf, sn, ss, sdB, t, out);
}